// Round 4
// baseline (1038.289 us; speedup 1.0000x reference)
//
#include <hip/hip_runtime.h>
#include <math.h>

#define BB   32
#define CC   512
#define NPIX 1600
#define KK   64
#define NT   25        // 64-wide n-tiles in pass A
#define EPSF 1e-12f

__device__ __forceinline__ void gl_lds16(const float* g, float* l) {
    __builtin_amdgcn_global_load_lds(
        (const __attribute__((address_space(1))) void*)g,
        (__attribute__((address_space(3))) void*)l, 16, 0, 0);
}

// ---------------------------------------------------------------------------
// k_wt: Wt[c][k] = w[k][c]   (one-time 128KB transpose, LDS-tiled)
// ---------------------------------------------------------------------------
__global__ __launch_bounds__(256) void k_wt(const float* __restrict__ w,
                                            float* __restrict__ wt) {
    __shared__ float tileS[64][65];
    int c0 = blockIdx.x * 64;
    int t = threadIdx.x;
    int kk = t >> 4, c4 = (t & 15) * 4;
#pragma unroll
    for (int i = 0; i < 4; ++i) {
        float4 v = *(const float4*)&w[(size_t)(kk + i * 16) * CC + c0 + c4];
        tileS[kk + i * 16][c4]     = v.x;
        tileS[kk + i * 16][c4 + 1] = v.y;
        tileS[kk + i * 16][c4 + 2] = v.z;
        tileS[kk + i * 16][c4 + 3] = v.w;
    }
    __syncthreads();
    int cc = t >> 2, kq = (t & 3) * 4;
#pragma unroll
    for (int i = 0; i < 4; ++i) {
        int k = kq + i * 16;
        *(float4*)&wt[(size_t)(c0 + cc) * KK + k] =
            make_float4(tileS[k][cc], tileS[k + 1][cc],
                        tileS[k + 2][cc], tileS[k + 3][cc]);
    }
}

// ---------------------------------------------------------------------------
// k_fused2: per (64n tile, b): logits GEMM (full C), ssq, softmax, a_t, asum_p.
// Both W (from wt) and X staged async via global_load_lds, double-buffered,
// one barrier per c-step. 256 thr: tn=t&15 (4 n), tg=t>>4 (4 k).
// ---------------------------------------------------------------------------
__global__ __launch_bounds__(256, 4) void k_fused2(const float* __restrict__ x,
                                                   const float* __restrict__ wt,
                                                   float* __restrict__ a_t,
                                                   float* __restrict__ invn,
                                                   float* __restrict__ asum_p) {
    int tile = blockIdx.x, b = blockIdx.y;
    int n0 = tile * 64;
    __shared__ __align__(16) float Xs[2][32 * 64];
    __shared__ __align__(16) float Ws[2][32 * 64];
    __shared__ __align__(16) float red[16 * 64];
    int t = threadIdx.x;
    int tn = t & 15, tg = t >> 4;
    int wv = t >> 6, lane = t & 63;
    int wrl = lane >> 4, wcl = (lane & 15) * 4;
    const float* xb = x + (size_t)b * CC * NPIX + n0;
    float acc[4][4] = {};
    float ssp[4] = {};

    // prologue: stage c-block 0
#pragma unroll
    for (int i = 0; i < 2; ++i) {
        int r = wv * 8 + i * 4;
        gl_lds16(&wt[(size_t)(r + wrl) * KK + wcl], &Ws[0][r * 64]);
        gl_lds16(&xb[(size_t)(r + wrl) * NPIX + wcl], &Xs[0][r * 64]);
    }
    __syncthreads();

    int cur = 0;
    for (int it = 0; it < 16; ++it) {
        if (it < 15) {
            int cg = (it + 1) * 32;
#pragma unroll
            for (int i = 0; i < 2; ++i) {
                int r = wv * 8 + i * 4;
                gl_lds16(&wt[(size_t)(cg + r + wrl) * KK + wcl], &Ws[cur ^ 1][r * 64]);
                gl_lds16(&xb[(size_t)(cg + r + wrl) * NPIX + wcl], &Xs[cur ^ 1][r * 64]);
            }
        }
        const float* Xc = Xs[cur];
        const float* Wc = Ws[cur];
#pragma unroll
        for (int cc = 0; cc < 32; ++cc) {
            float4 wv4 = *(const float4*)&Wc[cc * 64 + tg * 4];
            float4 xv4 = *(const float4*)&Xc[cc * 64 + tn * 4];
            float wa[4] = {wv4.x, wv4.y, wv4.z, wv4.w};
            float xa[4] = {xv4.x, xv4.y, xv4.z, xv4.w};
#pragma unroll
            for (int i = 0; i < 4; ++i)
#pragma unroll
                for (int j = 0; j < 4; ++j)
                    acc[i][j] = fmaf(wa[i], xa[j], acc[i][j]);
        }
        // ssq side-pass: this thread owns cc = tg*2 + {0,1} of current block
#pragma unroll
        for (int j2 = 0; j2 < 2; ++j2) {
            float4 xq = *(const float4*)&Xc[(tg * 2 + j2) * 64 + tn * 4];
            ssp[0] = fmaf(xq.x, xq.x, ssp[0]);
            ssp[1] = fmaf(xq.y, xq.y, ssp[1]);
            ssp[2] = fmaf(xq.z, xq.z, ssp[2]);
            ssp[3] = fmaf(xq.w, xq.w, ssp[3]);
        }
        __syncthreads();
        cur ^= 1;
    }

    // reduce ssq over 16 tg groups -> invn
    *(float4*)&red[tg * 64 + tn * 4] = make_float4(ssp[0], ssp[1], ssp[2], ssp[3]);
    __syncthreads();
#pragma unroll
    for (int off = 8; off >= 1; off >>= 1) {
        if (tg < off) {
#pragma unroll
            for (int j = 0; j < 4; ++j)
                red[tg * 64 + tn * 4 + j] += red[(tg + off) * 64 + tn * 4 + j];
        }
        __syncthreads();
    }
    if (t < 64) {
        float iv0 = 1.f / fmaxf(sqrtf(red[t]), EPSF);
        invn[b * NPIX + n0 + t] = iv0;
        red[t] = iv0;
    }
    __syncthreads();
    float iv[4];
#pragma unroll
    for (int j = 0; j < 4; ++j) iv[j] = red[tn * 4 + j];
    __syncthreads();

    // softmax over k
    float l[4][4], lm[4];
#pragma unroll
    for (int j = 0; j < 4; ++j) {
#pragma unroll
        for (int i = 0; i < 4; ++i) l[i][j] = acc[i][j] * iv[j];
        lm[j] = fmaxf(fmaxf(l[0][j], l[1][j]), fmaxf(l[2][j], l[3][j]));
    }
    *(float4*)&red[tg * 64 + tn * 4] = make_float4(lm[0], lm[1], lm[2], lm[3]);
    __syncthreads();
#pragma unroll
    for (int off = 8; off >= 1; off >>= 1) {
        if (tg < off) {
#pragma unroll
            for (int j = 0; j < 4; ++j) {
                int idx = tg * 64 + tn * 4 + j;
                red[idx] = fmaxf(red[idx], red[(tg + off) * 64 + tn * 4 + j]);
            }
        }
        __syncthreads();
    }
    float m[4];
#pragma unroll
    for (int j = 0; j < 4; ++j) m[j] = red[tn * 4 + j];
    __syncthreads();

    float e[4][4], ls[4];
#pragma unroll
    for (int j = 0; j < 4; ++j) {
        ls[j] = 0.f;
#pragma unroll
        for (int i = 0; i < 4; ++i) {
            e[i][j] = expf(l[i][j] - m[j]);
            ls[j] += e[i][j];
        }
    }
    *(float4*)&red[tg * 64 + tn * 4] = make_float4(ls[0], ls[1], ls[2], ls[3]);
    __syncthreads();
#pragma unroll
    for (int off = 8; off >= 1; off >>= 1) {
        if (tg < off) {
#pragma unroll
            for (int j = 0; j < 4; ++j) {
                int idx = tg * 64 + tn * 4 + j;
                red[idx] += red[(tg + off) * 64 + tn * 4 + j];
            }
        }
        __syncthreads();
    }

    float p[4] = {};
#pragma unroll
    for (int j = 0; j < 4; ++j) {
        float sd = 1.f / red[tn * 4 + j];
        float4 o = make_float4(e[0][j] * sd, e[1][j] * sd, e[2][j] * sd, e[3][j] * sd);
        *(float4*)&a_t[((size_t)b * NPIX + n0 + tn * 4 + j) * KK + tg * 4] = o;
        p[0] += o.x; p[1] += o.y; p[2] += o.z; p[3] += o.w;
    }
#pragma unroll
    for (int off = 1; off < 16; off <<= 1) {
#pragma unroll
        for (int i = 0; i < 4; ++i) p[i] += __shfl_xor(p[i], off, 64);
    }
    if (tn == 0) {
#pragma unroll
        for (int i = 0; i < 4; ++i)
            asum_p[((size_t)b * KK + tg * 4 + i) * NT + tile] = p[i];
    }
}

// ---------------------------------------------------------------------------
// k_vlad2: part[s][b][k][c] = sum_{n in chunk s} a[n,k] invn[n] x[c,n]
// grid (8 c-tiles x64, ns, 32 b), 256 thr: tc=t&15 (4 c), tg=t>>4 (4 k).
// As via glds (linear), Xs granule-XOR swizzled transpose, dbuf, 1 barrier/it.
// ---------------------------------------------------------------------------
__global__ __launch_bounds__(256, 4) void k_vlad2(const float* __restrict__ a_t,
                                                  const float* __restrict__ x,
                                                  const float* __restrict__ invn,
                                                  float* __restrict__ part,
                                                  int nchunk) {
    int c0 = blockIdx.x * 64;
    int s  = blockIdx.y;
    int b  = blockIdx.z;
    __shared__ __align__(16) float As[2][32 * 64];
    __shared__ __align__(16) float Xs[2][32 * 64];
    int t = threadIdx.x;
    int tc = t & 15, tg = t >> 4;
    int wv = t >> 6, lane = t & 63;
    float acc[4][4] = {};
    const float* ab  = a_t + (size_t)b * NPIX * KK;
    const float* xb  = x + (size_t)b * CC * NPIX;
    const float* ivb = invn + b * NPIX;
    int nbase = s * nchunk;
    int niters = nchunk / 32;
    int n4 = t & 7, c5 = t >> 3;                 // staging: nn=n4*4+q, cc=c5(+32)
    int colA = ((((t >> 5)    ) ^ n4) << 2) | (c5 & 3);  // granule swz, cc<32
    int colB = ((((t >> 5) + 8) ^ n4) << 2) | (c5 & 3);  // cc>=32

    // prologue: stage iter 0 into buf 0
    {
#pragma unroll
        for (int i = 0; i < 2; ++i) {
            int r = wv * 8 + i * 4;
            gl_lds16(&ab[(size_t)(nbase + r) * KK + lane * 4], &As[0][r * 64]);
        }
        float4 iv4 = *(const float4*)&ivb[nbase + n4 * 4];
        float4 x0 = *(const float4*)&xb[(size_t)(c0 + c5) * NPIX + nbase + n4 * 4];
        float4 x1 = *(const float4*)&xb[(size_t)(c0 + c5 + 32) * NPIX + nbase + n4 * 4];
        float* Xn = Xs[0];
        Xn[(n4 * 4 + 0) * 64 + colA] = x0.x * iv4.x;
        Xn[(n4 * 4 + 1) * 64 + colA] = x0.y * iv4.y;
        Xn[(n4 * 4 + 2) * 64 + colA] = x0.z * iv4.z;
        Xn[(n4 * 4 + 3) * 64 + colA] = x0.w * iv4.w;
        Xn[(n4 * 4 + 0) * 64 + colB] = x1.x * iv4.x;
        Xn[(n4 * 4 + 1) * 64 + colB] = x1.y * iv4.y;
        Xn[(n4 * 4 + 2) * 64 + colB] = x1.z * iv4.z;
        Xn[(n4 * 4 + 3) * 64 + colB] = x1.w * iv4.w;
    }
    __syncthreads();

    int cur = 0;
    for (int it = 0; it < niters; ++it) {
        bool pre = (it + 1 < niters);
        float4 x0, x1, iv4;
        if (pre) {
            int ng = nbase + (it + 1) * 32;
#pragma unroll
            for (int i = 0; i < 2; ++i) {
                int r = wv * 8 + i * 4;
                gl_lds16(&ab[(size_t)(ng + r) * KK + lane * 4], &As[cur ^ 1][r * 64]);
            }
            iv4 = *(const float4*)&ivb[ng + n4 * 4];
            x0 = *(const float4*)&xb[(size_t)(c0 + c5) * NPIX + ng + n4 * 4];
            x1 = *(const float4*)&xb[(size_t)(c0 + c5 + 32) * NPIX + ng + n4 * 4];
        }
        const float* Ac = As[cur];
        const float* Xc = Xs[cur];
#pragma unroll
        for (int nn = 0; nn < 32; ++nn) {
            float4 av = *(const float4*)&Ac[nn * 64 + tg * 4];
            float4 xv = *(const float4*)&Xc[nn * 64 + ((tc ^ (nn >> 2)) << 2)];
            float aa[4] = {av.x, av.y, av.z, av.w};
            float xa[4] = {xv.x, xv.y, xv.z, xv.w};
#pragma unroll
            for (int i = 0; i < 4; ++i)
#pragma unroll
                for (int j = 0; j < 4; ++j)
                    acc[i][j] = fmaf(aa[i], xa[j], acc[i][j]);
        }
        if (pre) {
            float* Xn = Xs[cur ^ 1];
            Xn[(n4 * 4 + 0) * 64 + colA] = x0.x * iv4.x;
            Xn[(n4 * 4 + 1) * 64 + colA] = x0.y * iv4.y;
            Xn[(n4 * 4 + 2) * 64 + colA] = x0.z * iv4.z;
            Xn[(n4 * 4 + 3) * 64 + colA] = x0.w * iv4.w;
            Xn[(n4 * 4 + 0) * 64 + colB] = x1.x * iv4.x;
            Xn[(n4 * 4 + 1) * 64 + colB] = x1.y * iv4.y;
            Xn[(n4 * 4 + 2) * 64 + colB] = x1.z * iv4.z;
            Xn[(n4 * 4 + 3) * 64 + colB] = x1.w * iv4.w;
        }
        __syncthreads();
        cur ^= 1;
    }
#pragma unroll
    for (int i = 0; i < 4; ++i) {
        int k = tg * 4 + i;
        *(float4*)&part[(((size_t)s * BB + b) * KK + k) * CC + c0 + tc * 4] =
            make_float4(acc[i][0], acc[i][1], acc[i][2], acc[i][3]);
    }
}

// ---------------------------------------------------------------------------
// k_intra: sum ns partials, asum from tile-partials, subtract asum*cent,
// intra-normalize per (b,k), accumulate per-b sum of squares.
// ---------------------------------------------------------------------------
__global__ __launch_bounds__(256) void k_intra(const float* __restrict__ part, int ns,
                                               const float* __restrict__ asum_p,
                                               const float* __restrict__ cent,
                                               float* __restrict__ out,
                                               float* __restrict__ bsum) {
    int row = blockIdx.x;                          // b*KK + k
    int b = row >> 6, k = row & 63;
    int t = threadIdx.x;
    float v0 = 0.f, v1 = 0.f;
    for (int s2 = 0; s2 < ns; ++s2) {
        const float* p = part + (((size_t)s2 * BB + b) * KK + k) * CC;
        v0 += p[t];
        v1 += p[t + 256];
    }
    float as = 0.f;
#pragma unroll
    for (int i = 0; i < NT; ++i) as += asum_p[(size_t)row * NT + i];
    v0 -= as * cent[k * CC + t];
    v1 -= as * cent[k * CC + t + 256];
    float ssq = v0 * v0 + v1 * v1;
#pragma unroll
    for (int off = 32; off; off >>= 1) ssq += __shfl_down(ssq, off, 64);
    __shared__ float red[4];
    __shared__ float s_inv;
    if ((t & 63) == 0) red[t >> 6] = ssq;
    __syncthreads();
    if (t == 0) {
        float sm = red[0] + red[1] + red[2] + red[3];
        float inv = 1.f / fmaxf(sqrtf(sm), EPSF);
        s_inv = inv;
        atomicAdd(&bsum[b], sm * inv * inv);
    }
    __syncthreads();
    float inv = s_inv;
    out[(size_t)row * CC + t]       = v0 * inv;
    out[(size_t)row * CC + t + 256] = v1 * inv;
}

// ---------------------------------------------------------------------------
__global__ __launch_bounds__(256) void k_scale(float* __restrict__ out,
                                               const float* __restrict__ bsum) {
    int idx = blockIdx.x * 256 + threadIdx.x;      // B*K*C exact
    int b = idx >> 15;                             // K*C = 32768
    out[idx] *= 1.f / fmaxf(sqrtf(bsum[b]), EPSF);
}

// ---------------------------------------------------------------------------
extern "C" void kernel_launch(void* const* d_in, const int* in_sizes, int n_in,
                              void* d_out, int out_size, void* d_ws, size_t ws_size,
                              hipStream_t stream) {
    const float* x    = (const float*)d_in[0];   // [B,C,H,W]
    const float* cent = (const float*)d_in[1];   // [K,C]
    const float* w    = (const float*)d_in[2];   // [K,C]
    float* out = (float*)d_out;

    float* ws = (float*)d_ws;
    const size_t o_at   = 0;                      // B*N*K   = 3,276,800
    const size_t o_invn = 3276800;                // B*N     =    51,200
    const size_t o_asum = o_invn + 51200;         // B*K*NT  =    51,200
    const size_t o_bsum = o_asum + 51200;         // 64
    const size_t o_wt   = o_bsum + 64;            // C*K     =    32,768
    const size_t o_part = o_wt + 32768;           // ns * B*K*C

    const size_t pelems = (size_t)BB * KK * CC;   // 1,048,576 per partial
    int ns = 0;
    const int cand[3] = {5, 2, 1};
    for (int i = 0; i < 3; ++i) {
        if ((o_part + (size_t)cand[i] * pelems) * 4 <= ws_size) { ns = cand[i]; break; }
    }
    float* part = (ns > 0) ? (ws + o_part) : out;
    if (ns == 0) ns = 1;
    int nchunk = NPIX / ns;

    hipMemsetAsync(ws + o_bsum, 0, BB * sizeof(float), stream);

    k_wt    <<<dim3(8), 256, 0, stream>>>(w, ws + o_wt);
    k_fused2<<<dim3(NT, BB), 256, 0, stream>>>(x, ws + o_wt, ws + o_at,
                                               ws + o_invn, ws + o_asum);
    k_vlad2 <<<dim3(8, ns, BB), 256, 0, stream>>>(ws + o_at, x, ws + o_invn, part, nchunk);
    k_intra <<<dim3(BB * KK), 256, 0, stream>>>(part, ns, ws + o_asum, cent, out, ws + o_bsum);
    k_scale <<<dim3((BB * KK * CC) / 256), 256, 0, stream>>>(out, ws + o_bsum);
}

// Round 5
// 242.417 us; speedup vs baseline: 4.2831x; 4.2831x over previous
//
#include <hip/hip_runtime.h>
#include <math.h>

#define BB   32
#define CC   512
#define NPIX 1600
#define KK   64
#define NT   25        // 64-wide n-tiles in pass A
#define EPSF 1e-12f

__device__ __forceinline__ void gl_lds16(const float* g, float* l) {
    __builtin_amdgcn_global_load_lds(
        (const __attribute__((address_space(1))) void*)g,
        (__attribute__((address_space(3))) void*)l, 16, 0, 0);
}

// ---------------------------------------------------------------------------
// k_wt: Wt[c][k] = w[k][c]   (one-time 128KB transpose, LDS-tiled)
// ---------------------------------------------------------------------------
__global__ __launch_bounds__(256) void k_wt(const float* __restrict__ w,
                                            float* __restrict__ wt) {
    __shared__ float tileS[64][65];
    int c0 = blockIdx.x * 64;
    int t = threadIdx.x;
    int kk = t >> 4, c4 = (t & 15) * 4;
#pragma unroll
    for (int i = 0; i < 4; ++i) {
        float4 v = *(const float4*)&w[(size_t)(kk + i * 16) * CC + c0 + c4];
        tileS[kk + i * 16][c4]     = v.x;
        tileS[kk + i * 16][c4 + 1] = v.y;
        tileS[kk + i * 16][c4 + 2] = v.z;
        tileS[kk + i * 16][c4 + 3] = v.w;
    }
    __syncthreads();
    int cc = t >> 2, kq = (t & 3) * 4;
#pragma unroll
    for (int i = 0; i < 4; ++i) {
        int k = kq + i * 16;
        *(float4*)&wt[(size_t)(c0 + cc) * KK + k] =
            make_float4(tileS[k][cc], tileS[k + 1][cc],
                        tileS[k + 2][cc], tileS[k + 3][cc]);
    }
}

// ---------------------------------------------------------------------------
// k_fused3: per (64n tile, b): logits GEMM (full C), ssq, softmax, a_t, asum_p.
// W and X staged async via global_load_lds (clean sources only), dbuf, one
// barrier per c-step.  FMA: 4-wave c-slicing — wave w handles cc in
// [w*8, w*8+8) of each 32-c block with an 8k x 8n per-thread tile
// (4 b128 reads : 64 FMA), then a serialized LDS tree-combine.
// ---------------------------------------------------------------------------
__global__ __launch_bounds__(256, 4) void k_fused3(const float* __restrict__ x,
                                                   const float* __restrict__ wt,
                                                   float* __restrict__ a_t,
                                                   float* __restrict__ invn,
                                                   float* __restrict__ asum_p) {
    int tile = blockIdx.x, b = blockIdx.y;
    int n0 = tile * 64;
    __shared__ __align__(16) float Xs[2][32 * 64];
    __shared__ __align__(16) float Ws[2][32 * 64];
    __shared__ __align__(16) float red[16 * 64];
    int t = threadIdx.x;
    int tn = t & 15, tg = t >> 4;          // epilogue mapping (4k x 4n)
    int w  = t >> 6, lane = t & 63;        // wave id / lane
    int kg = (t >> 3) & 7, ng = t & 7;     // FMA mapping (8k x 8n per thread)
    int wrl = lane >> 4, wcl = (lane & 15) * 4;
    const float* xb = x + (size_t)b * CC * NPIX + n0;
    float acc[8][8] = {};
    float ssp[4] = {};

    // prologue: stage c-block 0
#pragma unroll
    for (int i = 0; i < 2; ++i) {
        int r = w * 8 + i * 4;
        gl_lds16(&wt[(size_t)(r + wrl) * KK + wcl], &Ws[0][r * 64]);
        gl_lds16(&xb[(size_t)(r + wrl) * NPIX + wcl], &Xs[0][r * 64]);
    }
    __syncthreads();

    int cur = 0;
    for (int it = 0; it < 16; ++it) {
        if (it < 15) {
            int cg = (it + 1) * 32;
#pragma unroll
            for (int i = 0; i < 2; ++i) {
                int r = w * 8 + i * 4;
                gl_lds16(&wt[(size_t)(cg + r + wrl) * KK + wcl], &Ws[cur ^ 1][r * 64]);
                gl_lds16(&xb[(size_t)(cg + r + wrl) * NPIX + wcl], &Xs[cur ^ 1][r * 64]);
            }
        }
        const float* Xc = Xs[cur];
        const float* Wc = Ws[cur];
        // wave w multiplies its 8-c slice of this 32-c block
#pragma unroll
        for (int ci = 0; ci < 8; ++ci) {
            int cc = w * 8 + ci;
            float4 w0 = *(const float4*)&Wc[cc * 64 + kg * 8];
            float4 w1 = *(const float4*)&Wc[cc * 64 + kg * 8 + 4];
            float4 x0 = *(const float4*)&Xc[cc * 64 + ng * 8];
            float4 x1 = *(const float4*)&Xc[cc * 64 + ng * 8 + 4];
            float wa[8] = {w0.x, w0.y, w0.z, w0.w, w1.x, w1.y, w1.z, w1.w};
            float xa[8] = {x0.x, x0.y, x0.z, x0.w, x1.x, x1.y, x1.z, x1.w};
#pragma unroll
            for (int i = 0; i < 8; ++i)
#pragma unroll
                for (int j = 0; j < 8; ++j)
                    acc[i][j] = fmaf(wa[i], xa[j], acc[i][j]);
        }
        // ssq side-pass over the full 32-c block (rows tg*2, tg*2+1)
#pragma unroll
        for (int j2 = 0; j2 < 2; ++j2) {
            float4 xq = *(const float4*)&Xc[(tg * 2 + j2) * 64 + tn * 4];
            ssp[0] = fmaf(xq.x, xq.x, ssp[0]);
            ssp[1] = fmaf(xq.y, xq.y, ssp[1]);
            ssp[2] = fmaf(xq.z, xq.z, ssp[2]);
            ssp[3] = fmaf(xq.w, xq.w, ssp[3]);
        }
        __syncthreads();
        cur ^= 1;
    }

    // cross-wave combine of the c-sliced partial tiles into T (= Ws storage)
    float* T = &Ws[0][0];                  // 64x64 = 16KB
    for (int w2 = 0; w2 < 4; ++w2) {
        if (w == w2) {
#pragma unroll
            for (int i = 0; i < 8; ++i) {
                int row = kg * 8 + i;
                if (w2 == 0) {
                    *(float4*)&T[row * 64 + ng * 8] =
                        make_float4(acc[i][0], acc[i][1], acc[i][2], acc[i][3]);
                    *(float4*)&T[row * 64 + ng * 8 + 4] =
                        make_float4(acc[i][4], acc[i][5], acc[i][6], acc[i][7]);
                } else {
                    float4 t0 = *(float4*)&T[row * 64 + ng * 8];
                    float4 t1 = *(float4*)&T[row * 64 + ng * 8 + 4];
                    t0.x += acc[i][0]; t0.y += acc[i][1];
                    t0.z += acc[i][2]; t0.w += acc[i][3];
                    t1.x += acc[i][4]; t1.y += acc[i][5];
                    t1.z += acc[i][6]; t1.w += acc[i][7];
                    *(float4*)&T[row * 64 + ng * 8]     = t0;
                    *(float4*)&T[row * 64 + ng * 8 + 4] = t1;
                }
            }
        }
        __syncthreads();
    }

    // reduce ssq over 16 tg groups -> invn
    *(float4*)&red[tg * 64 + tn * 4] = make_float4(ssp[0], ssp[1], ssp[2], ssp[3]);
    __syncthreads();
#pragma unroll
    for (int off = 8; off >= 1; off >>= 1) {
        if (tg < off) {
#pragma unroll
            for (int j = 0; j < 4; ++j)
                red[tg * 64 + tn * 4 + j] += red[(tg + off) * 64 + tn * 4 + j];
        }
        __syncthreads();
    }
    if (t < 64) {
        float iv0 = 1.f / fmaxf(sqrtf(red[t]), EPSF);
        invn[b * NPIX + n0 + t] = iv0;
        red[t] = iv0;
    }
    __syncthreads();
    float iv[4];
#pragma unroll
    for (int j = 0; j < 4; ++j) iv[j] = red[tn * 4 + j];
    __syncthreads();

    // softmax over k (epilogue in old 4k x 4n mapping, sourced from T)
    float l[4][4], lm[4];
#pragma unroll
    for (int i = 0; i < 4; ++i) {
        float4 lv = *(const float4*)&T[(tg * 4 + i) * 64 + tn * 4];
        l[i][0] = lv.x * iv[0];
        l[i][1] = lv.y * iv[1];
        l[i][2] = lv.z * iv[2];
        l[i][3] = lv.w * iv[3];
    }
#pragma unroll
    for (int j = 0; j < 4; ++j)
        lm[j] = fmaxf(fmaxf(l[0][j], l[1][j]), fmaxf(l[2][j], l[3][j]));
    __syncthreads();   // done reading T before red-tree reuses nothing of it; keep order safe
    *(float4*)&red[tg * 64 + tn * 4] = make_float4(lm[0], lm[1], lm[2], lm[3]);
    __syncthreads();
#pragma unroll
    for (int off = 8; off >= 1; off >>= 1) {
        if (tg < off) {
#pragma unroll
            for (int j = 0; j < 4; ++j) {
                int idx = tg * 64 + tn * 4 + j;
                red[idx] = fmaxf(red[idx], red[(tg + off) * 64 + tn * 4 + j]);
            }
        }
        __syncthreads();
    }
    float m[4];
#pragma unroll
    for (int j = 0; j < 4; ++j) m[j] = red[tn * 4 + j];
    __syncthreads();

    float e[4][4], ls[4];
#pragma unroll
    for (int j = 0; j < 4; ++j) {
        ls[j] = 0.f;
#pragma unroll
        for (int i = 0; i < 4; ++i) {
            e[i][j] = expf(l[i][j] - m[j]);
            ls[j] += e[i][j];
        }
    }
    *(float4*)&red[tg * 64 + tn * 4] = make_float4(ls[0], ls[1], ls[2], ls[3]);
    __syncthreads();
#pragma unroll
    for (int off = 8; off >= 1; off >>= 1) {
        if (tg < off) {
#pragma unroll
            for (int j = 0; j < 4; ++j) {
                int idx = tg * 64 + tn * 4 + j;
                red[idx] += red[(tg + off) * 64 + tn * 4 + j];
            }
        }
        __syncthreads();
    }

    float p[4] = {};
#pragma unroll
    for (int j = 0; j < 4; ++j) {
        float sd = 1.f / red[tn * 4 + j];
        float4 o = make_float4(e[0][j] * sd, e[1][j] * sd, e[2][j] * sd, e[3][j] * sd);
        *(float4*)&a_t[((size_t)b * NPIX + n0 + tn * 4 + j) * KK + tg * 4] = o;
        p[0] += o.x; p[1] += o.y; p[2] += o.z; p[3] += o.w;
    }
#pragma unroll
    for (int off = 1; off < 16; off <<= 1) {
#pragma unroll
        for (int i = 0; i < 4; ++i) p[i] += __shfl_xor(p[i], off, 64);
    }
    if (tn == 0) {
#pragma unroll
        for (int i = 0; i < 4; ++i)
            asum_p[((size_t)b * KK + tg * 4 + i) * NT + tile] = p[i];
    }
}

// ---------------------------------------------------------------------------
// k_vlad3: part[s][b][k][c] = sum_{n in chunk s} a[n,k] invn[n] x[c,n]
// 128 thr, tile 64k x 128c, 8k x 8c per thread.  As: plain b128 copy
// (a_t rows linear — NO global_load_lds on dirty intermediates).
// Xs: [32n][128c] with XOR granule swizzle col = 4*((c>>2)^ (n>>2... stored
// per-row key n4) + (c&3); verified <=2 lanes/bank on all accesses.
// Single-buffer, 2 barriers per 32-n step.  grid (4, ns, 32).
// ---------------------------------------------------------------------------
__global__ __launch_bounds__(128, 3) void k_vlad3(const float* __restrict__ a_t,
                                                  const float* __restrict__ x,
                                                  const float* __restrict__ invn,
                                                  float* __restrict__ part,
                                                  int nchunk) {
    int c0 = blockIdx.x * 128;
    int s  = blockIdx.y;
    int b  = blockIdx.z;
    __shared__ __align__(16) float As[32 * 64];    // [nn][k]
    __shared__ __align__(16) float Xs[32 * 128];   // [nn][swz(c)]
    int t  = threadIdx.x;
    int kg = t >> 4;            // 0..7   (8 k per thread)
    int cg = t & 15;            // 0..15  (8 c per thread)
    int n4 = t & 7;             // X staging n-group
    int cb = t >> 3;            // X staging c base (0..15)
    float acc[8][8] = {};
    const float* xb  = x + (size_t)b * CC * NPIX;
    const float* ivb = invn + b * NPIX;
    int nbase = s * nchunk;
    int niters = nchunk / 32;

    for (int it = 0; it < niters; ++it) {
        int n0 = nbase + it * 32;
        // As: linear coalesced copy, 16B/lane contiguous
        const float* ar = a_t + ((size_t)b * NPIX + n0) * KK;
#pragma unroll
        for (int i = 0; i < 4; ++i)
            *(float4*)&As[t * 16 + i * 4] = *(const float4*)&ar[t * 16 + i * 4];
        // Xs: transpose + invn scale + XOR swizzle
        float4 iv4 = *(const float4*)&ivb[n0 + n4 * 4];
        float ivr[4] = {iv4.x, iv4.y, iv4.z, iv4.w};
#pragma unroll
        for (int i = 0; i < 8; ++i) {
            int c = cb + 16 * i;
            float4 xv = *(const float4*)&xb[(size_t)(c0 + c) * NPIX + n0 + n4 * 4];
            int col = 4 * (((c >> 2) ^ n4) & 31) + (c & 3);
            Xs[(n4 * 4 + 0) * 128 + col] = xv.x * ivr[0];
            Xs[(n4 * 4 + 1) * 128 + col] = xv.y * ivr[1];
            Xs[(n4 * 4 + 2) * 128 + col] = xv.z * ivr[2];
            Xs[(n4 * 4 + 3) * 128 + col] = xv.w * ivr[3];
        }
        __syncthreads();
#pragma unroll
        for (int nn = 0; nn < 32; ++nn) {
            int sx = nn >> 2;
            float4 a0 = *(const float4*)&As[nn * 64 + kg * 8];
            float4 a1 = *(const float4*)&As[nn * 64 + kg * 8 + 4];
            float4 x0 = *(const float4*)&Xs[nn * 128 + 4 * ((cg * 2) ^ sx)];
            float4 x1 = *(const float4*)&Xs[nn * 128 + 4 * ((cg * 2 + 1) ^ sx)];
            float aa[8] = {a0.x, a0.y, a0.z, a0.w, a1.x, a1.y, a1.z, a1.w};
            float xa[8] = {x0.x, x0.y, x0.z, x0.w, x1.x, x1.y, x1.z, x1.w};
#pragma unroll
            for (int i = 0; i < 8; ++i)
#pragma unroll
                for (int j = 0; j < 8; ++j)
                    acc[i][j] = fmaf(aa[i], xa[j], acc[i][j]);
        }
        __syncthreads();
    }
#pragma unroll
    for (int i = 0; i < 8; ++i) {
        int k = kg * 8 + i;
        float* pp = &part[(((size_t)s * BB + b) * KK + k) * CC + c0 + cg * 8];
        *(float4*)&pp[0] = make_float4(acc[i][0], acc[i][1], acc[i][2], acc[i][3]);
        *(float4*)&pp[4] = make_float4(acc[i][4], acc[i][5], acc[i][6], acc[i][7]);
    }
}

// ---------------------------------------------------------------------------
// k_intra: sum ns partials, asum from tile-partials, subtract asum*cent,
// intra-normalize per (b,k), accumulate per-b sum of squares.
// ---------------------------------------------------------------------------
__global__ __launch_bounds__(256) void k_intra(const float* __restrict__ part, int ns,
                                               const float* __restrict__ asum_p,
                                               const float* __restrict__ cent,
                                               float* __restrict__ out,
                                               float* __restrict__ bsum) {
    int row = blockIdx.x;                          // b*KK + k
    int b = row >> 6, k = row & 63;
    int t = threadIdx.x;
    float v0 = 0.f, v1 = 0.f;
    for (int s2 = 0; s2 < ns; ++s2) {
        const float* p = part + (((size_t)s2 * BB + b) * KK + k) * CC;
        v0 += p[t];
        v1 += p[t + 256];
    }
    float as = 0.f;
#pragma unroll
    for (int i = 0; i < NT; ++i) as += asum_p[(size_t)row * NT + i];
    v0 -= as * cent[k * CC + t];
    v1 -= as * cent[k * CC + t + 256];
    float ssq = v0 * v0 + v1 * v1;
#pragma unroll
    for (int off = 32; off; off >>= 1) ssq += __shfl_down(ssq, off, 64);
    __shared__ float red[4];
    __shared__ float s_inv;
    if ((t & 63) == 0) red[t >> 6] = ssq;
    __syncthreads();
    if (t == 0) {
        float sm = red[0] + red[1] + red[2] + red[3];
        float inv = 1.f / fmaxf(sqrtf(sm), EPSF);
        s_inv = inv;
        atomicAdd(&bsum[b], sm * inv * inv);
    }
    __syncthreads();
    float inv = s_inv;
    out[(size_t)row * CC + t]       = v0 * inv;
    out[(size_t)row * CC + t + 256] = v1 * inv;
}

// ---------------------------------------------------------------------------
__global__ __launch_bounds__(256) void k_scale(float* __restrict__ out,
                                               const float* __restrict__ bsum) {
    int idx = blockIdx.x * 256 + threadIdx.x;      // B*K*C exact
    int b = idx >> 15;                             // K*C = 32768
    out[idx] *= 1.f / fmaxf(sqrtf(bsum[b]), EPSF);
}

// ---------------------------------------------------------------------------
extern "C" void kernel_launch(void* const* d_in, const int* in_sizes, int n_in,
                              void* d_out, int out_size, void* d_ws, size_t ws_size,
                              hipStream_t stream) {
    const float* x    = (const float*)d_in[0];   // [B,C,H,W]
    const float* cent = (const float*)d_in[1];   // [K,C]
    const float* w    = (const float*)d_in[2];   // [K,C]
    float* out = (float*)d_out;

    float* ws = (float*)d_ws;
    const size_t o_at   = 0;                      // B*N*K   = 3,276,800
    const size_t o_invn = 3276800;                // B*N     =    51,200
    const size_t o_asum = o_invn + 51200;         // B*K*NT  =    51,200
    const size_t o_bsum = o_asum + 51200;         // 64
    const size_t o_wt   = o_bsum + 64;            // C*K     =    32,768
    const size_t o_part = o_wt + 32768;           // ns * B*K*C

    const size_t pelems = (size_t)BB * KK * CC;   // 1,048,576 per partial
    int ns = 0;
    const int cand[4] = {10, 5, 2, 1};
    for (int i = 0; i < 4; ++i) {
        if ((o_part + (size_t)cand[i] * pelems) * 4 <= ws_size) { ns = cand[i]; break; }
    }
    float* part = (ns > 0) ? (ws + o_part) : out;
    if (ns == 0) ns = 1;
    int nchunk = NPIX / ns;

    hipMemsetAsync(ws + o_bsum, 0, BB * sizeof(float), stream);

    k_wt    <<<dim3(8), 256, 0, stream>>>(w, ws + o_wt);
    k_fused3<<<dim3(NT, BB), 256, 0, stream>>>(x, ws + o_wt, ws + o_at,
                                               ws + o_invn, ws + o_asum);
    k_vlad3 <<<dim3(4, ns, BB), 128, 0, stream>>>(ws + o_at, x, ws + o_invn, part, nchunk);
    k_intra <<<dim3(BB * KK), 256, 0, stream>>>(part, ns, ws + o_asum, cent, out, ws + o_bsum);
    k_scale <<<dim3((BB * KK * CC) / 256), 256, 0, stream>>>(out, ws + o_bsum);
}

// Round 6
// 159.468 us; speedup vs baseline: 6.5110x; 1.5202x over previous
//
#include <hip/hip_runtime.h>
#include <math.h>

#define BB   32
#define CC   512
#define NPIX 1600
#define KK   64
#define NT   25        // 64-wide n-tiles in pass A
#define EPSF 1e-12f

__device__ __forceinline__ void gl_lds16(const float* g, float* l) {
    __builtin_amdgcn_global_load_lds(
        (const __attribute__((address_space(1))) void*)g,
        (__attribute__((address_space(3))) void*)l, 16, 0, 0);
}

// ---------------------------------------------------------------------------
// k_wt: Wt[c][k] = w[k][c]   (one-time 128KB transpose, LDS-tiled)
// ---------------------------------------------------------------------------
__global__ __launch_bounds__(256) void k_wt(const float* __restrict__ w,
                                            float* __restrict__ wt) {
    __shared__ float tileS[64][65];
    int c0 = blockIdx.x * 64;
    int t = threadIdx.x;
    int kk = t >> 4, c4 = (t & 15) * 4;
#pragma unroll
    for (int i = 0; i < 4; ++i) {
        float4 v = *(const float4*)&w[(size_t)(kk + i * 16) * CC + c0 + c4];
        tileS[kk + i * 16][c4]     = v.x;
        tileS[kk + i * 16][c4 + 1] = v.y;
        tileS[kk + i * 16][c4 + 2] = v.z;
        tileS[kk + i * 16][c4 + 3] = v.w;
    }
    __syncthreads();
    int cc = t >> 2, kq = (t & 3) * 4;
#pragma unroll
    for (int i = 0; i < 4; ++i) {
        int k = kq + i * 16;
        *(float4*)&wt[(size_t)(c0 + cc) * KK + k] =
            make_float4(tileS[k][cc], tileS[k + 1][cc],
                        tileS[k + 2][cc], tileS[k + 3][cc]);
    }
}

// ---------------------------------------------------------------------------
// k_fused3: per (64n tile, b): logits GEMM (full C), ssq, softmax, a_t, asum_p.
// W and X staged async via global_load_lds (clean sources only), dbuf, one
// barrier per c-step.  FMA: 4-wave c-slicing — wave w handles cc in
// [w*8, w*8+8) of each 32-c block with an 8k x 8n per-thread tile
// (4 b128 reads : 64 FMA), then a serialized LDS tree-combine.
// __launch_bounds__(256, 2): acc[8][8] needs 64 VGPRs; the (256,4) cap of 64
// total caused full accumulator spill (R5: WRITE_SIZE 200MB, dur 168us).
// ---------------------------------------------------------------------------
__global__ __launch_bounds__(256, 2) void k_fused3(const float* __restrict__ x,
                                                   const float* __restrict__ wt,
                                                   float* __restrict__ a_t,
                                                   float* __restrict__ invn,
                                                   float* __restrict__ asum_p) {
    int tile = blockIdx.x, b = blockIdx.y;
    int n0 = tile * 64;
    __shared__ __align__(16) float Xs[2][32 * 64];
    __shared__ __align__(16) float Ws[2][32 * 64];
    __shared__ __align__(16) float red[16 * 64];
    int t = threadIdx.x;
    int tn = t & 15, tg = t >> 4;          // epilogue mapping (4k x 4n)
    int w  = t >> 6, lane = t & 63;        // wave id / lane
    int kg = (t >> 3) & 7, ng = t & 7;     // FMA mapping (8k x 8n per thread)
    int wrl = lane >> 4, wcl = (lane & 15) * 4;
    const float* xb = x + (size_t)b * CC * NPIX + n0;
    float acc[8][8] = {};
    float ssp[4] = {};

    // prologue: stage c-block 0
#pragma unroll
    for (int i = 0; i < 2; ++i) {
        int r = w * 8 + i * 4;
        gl_lds16(&wt[(size_t)(r + wrl) * KK + wcl], &Ws[0][r * 64]);
        gl_lds16(&xb[(size_t)(r + wrl) * NPIX + wcl], &Xs[0][r * 64]);
    }
    __syncthreads();

    int cur = 0;
    for (int it = 0; it < 16; ++it) {
        if (it < 15) {
            int cg = (it + 1) * 32;
#pragma unroll
            for (int i = 0; i < 2; ++i) {
                int r = w * 8 + i * 4;
                gl_lds16(&wt[(size_t)(cg + r + wrl) * KK + wcl], &Ws[cur ^ 1][r * 64]);
                gl_lds16(&xb[(size_t)(cg + r + wrl) * NPIX + wcl], &Xs[cur ^ 1][r * 64]);
            }
        }
        const float* Xc = Xs[cur];
        const float* Wc = Ws[cur];
        // wave w multiplies its 8-c slice of this 32-c block
#pragma unroll
        for (int ci = 0; ci < 8; ++ci) {
            int cc = w * 8 + ci;
            float4 w0 = *(const float4*)&Wc[cc * 64 + kg * 8];
            float4 w1 = *(const float4*)&Wc[cc * 64 + kg * 8 + 4];
            float4 x0 = *(const float4*)&Xc[cc * 64 + ng * 8];
            float4 x1 = *(const float4*)&Xc[cc * 64 + ng * 8 + 4];
            float wa[8] = {w0.x, w0.y, w0.z, w0.w, w1.x, w1.y, w1.z, w1.w};
            float xa[8] = {x0.x, x0.y, x0.z, x0.w, x1.x, x1.y, x1.z, x1.w};
#pragma unroll
            for (int i = 0; i < 8; ++i)
#pragma unroll
                for (int j = 0; j < 8; ++j)
                    acc[i][j] = fmaf(wa[i], xa[j], acc[i][j]);
        }
        // ssq side-pass over the full 32-c block (rows tg*2, tg*2+1)
#pragma unroll
        for (int j2 = 0; j2 < 2; ++j2) {
            float4 xq = *(const float4*)&Xc[(tg * 2 + j2) * 64 + tn * 4];
            ssp[0] = fmaf(xq.x, xq.x, ssp[0]);
            ssp[1] = fmaf(xq.y, xq.y, ssp[1]);
            ssp[2] = fmaf(xq.z, xq.z, ssp[2]);
            ssp[3] = fmaf(xq.w, xq.w, ssp[3]);
        }
        __syncthreads();
        cur ^= 1;
    }

    // cross-wave combine of the c-sliced partial tiles into T (= Ws storage)
    float* T = &Ws[0][0];                  // 64x64 = 16KB
    for (int w2 = 0; w2 < 4; ++w2) {
        if (w == w2) {
#pragma unroll
            for (int i = 0; i < 8; ++i) {
                int row = kg * 8 + i;
                if (w2 == 0) {
                    *(float4*)&T[row * 64 + ng * 8] =
                        make_float4(acc[i][0], acc[i][1], acc[i][2], acc[i][3]);
                    *(float4*)&T[row * 64 + ng * 8 + 4] =
                        make_float4(acc[i][4], acc[i][5], acc[i][6], acc[i][7]);
                } else {
                    float4 t0 = *(float4*)&T[row * 64 + ng * 8];
                    float4 t1 = *(float4*)&T[row * 64 + ng * 8 + 4];
                    t0.x += acc[i][0]; t0.y += acc[i][1];
                    t0.z += acc[i][2]; t0.w += acc[i][3];
                    t1.x += acc[i][4]; t1.y += acc[i][5];
                    t1.z += acc[i][6]; t1.w += acc[i][7];
                    *(float4*)&T[row * 64 + ng * 8]     = t0;
                    *(float4*)&T[row * 64 + ng * 8 + 4] = t1;
                }
            }
        }
        __syncthreads();
    }

    // reduce ssq over 16 tg groups -> invn
    *(float4*)&red[tg * 64 + tn * 4] = make_float4(ssp[0], ssp[1], ssp[2], ssp[3]);
    __syncthreads();
#pragma unroll
    for (int off = 8; off >= 1; off >>= 1) {
        if (tg < off) {
#pragma unroll
            for (int j = 0; j < 4; ++j)
                red[tg * 64 + tn * 4 + j] += red[(tg + off) * 64 + tn * 4 + j];
        }
        __syncthreads();
    }
    if (t < 64) {
        float iv0 = 1.f / fmaxf(sqrtf(red[t]), EPSF);
        invn[b * NPIX + n0 + t] = iv0;
        red[t] = iv0;
    }
    __syncthreads();
    float iv[4];
#pragma unroll
    for (int j = 0; j < 4; ++j) iv[j] = red[tn * 4 + j];
    __syncthreads();

    // softmax over k (epilogue in old 4k x 4n mapping, sourced from T)
    float l[4][4], lm[4];
#pragma unroll
    for (int i = 0; i < 4; ++i) {
        float4 lv = *(const float4*)&T[(tg * 4 + i) * 64 + tn * 4];
        l[i][0] = lv.x * iv[0];
        l[i][1] = lv.y * iv[1];
        l[i][2] = lv.z * iv[2];
        l[i][3] = lv.w * iv[3];
    }
#pragma unroll
    for (int j = 0; j < 4; ++j)
        lm[j] = fmaxf(fmaxf(l[0][j], l[1][j]), fmaxf(l[2][j], l[3][j]));
    __syncthreads();
    *(float4*)&red[tg * 64 + tn * 4] = make_float4(lm[0], lm[1], lm[2], lm[3]);
    __syncthreads();
#pragma unroll
    for (int off = 8; off >= 1; off >>= 1) {
        if (tg < off) {
#pragma unroll
            for (int j = 0; j < 4; ++j) {
                int idx = tg * 64 + tn * 4 + j;
                red[idx] = fmaxf(red[idx], red[(tg + off) * 64 + tn * 4 + j]);
            }
        }
        __syncthreads();
    }
    float m[4];
#pragma unroll
    for (int j = 0; j < 4; ++j) m[j] = red[tn * 4 + j];
    __syncthreads();

    float e[4][4], ls[4];
#pragma unroll
    for (int j = 0; j < 4; ++j) {
        ls[j] = 0.f;
#pragma unroll
        for (int i = 0; i < 4; ++i) {
            e[i][j] = expf(l[i][j] - m[j]);
            ls[j] += e[i][j];
        }
    }
    *(float4*)&red[tg * 64 + tn * 4] = make_float4(ls[0], ls[1], ls[2], ls[3]);
    __syncthreads();
#pragma unroll
    for (int off = 8; off >= 1; off >>= 1) {
        if (tg < off) {
#pragma unroll
            for (int j = 0; j < 4; ++j) {
                int idx = tg * 64 + tn * 4 + j;
                red[idx] += red[(tg + off) * 64 + tn * 4 + j];
            }
        }
        __syncthreads();
    }

    float p[4] = {};
#pragma unroll
    for (int j = 0; j < 4; ++j) {
        float sd = 1.f / red[tn * 4 + j];
        float4 o = make_float4(e[0][j] * sd, e[1][j] * sd, e[2][j] * sd, e[3][j] * sd);
        *(float4*)&a_t[((size_t)b * NPIX + n0 + tn * 4 + j) * KK + tg * 4] = o;
        p[0] += o.x; p[1] += o.y; p[2] += o.z; p[3] += o.w;
    }
#pragma unroll
    for (int off = 1; off < 16; off <<= 1) {
#pragma unroll
        for (int i = 0; i < 4; ++i) p[i] += __shfl_xor(p[i], off, 64);
    }
    if (tn == 0) {
#pragma unroll
        for (int i = 0; i < 4; ++i)
            asum_p[((size_t)b * KK + tg * 4 + i) * NT + tile] = p[i];
    }
}

// ---------------------------------------------------------------------------
// k_vlad3: part[s][b][k][c] = sum_{n in chunk s} a[n,k] invn[n] x[c,n]
// 128 thr, tile 64k x 128c, 8k x 8c per thread.  As: plain b128 copy
// (a_t rows linear — NO global_load_lds on dirty intermediates).
// Xs: XOR granule swizzle; single-buffer, 2 barriers/step.  grid (4, ns, 32).
// ---------------------------------------------------------------------------
__global__ __launch_bounds__(128, 3) void k_vlad3(const float* __restrict__ a_t,
                                                  const float* __restrict__ x,
                                                  const float* __restrict__ invn,
                                                  float* __restrict__ part,
                                                  int nchunk) {
    int c0 = blockIdx.x * 128;
    int s  = blockIdx.y;
    int b  = blockIdx.z;
    __shared__ __align__(16) float As[32 * 64];    // [nn][k]
    __shared__ __align__(16) float Xs[32 * 128];   // [nn][swz(c)]
    int t  = threadIdx.x;
    int kg = t >> 4;            // 0..7   (8 k per thread)
    int cg = t & 15;            // 0..15  (8 c per thread)
    int n4 = t & 7;             // X staging n-group
    int cb = t >> 3;            // X staging c base (0..15)
    float acc[8][8] = {};
    const float* xb  = x + (size_t)b * CC * NPIX;
    const float* ivb = invn + b * NPIX;
    int nbase = s * nchunk;
    int niters = nchunk / 32;

    for (int it = 0; it < niters; ++it) {
        int n0 = nbase + it * 32;
        // As: linear coalesced copy, 16B/lane contiguous
        const float* ar = a_t + ((size_t)b * NPIX + n0) * KK;
#pragma unroll
        for (int i = 0; i < 4; ++i)
            *(float4*)&As[t * 16 + i * 4] = *(const float4*)&ar[t * 16 + i * 4];
        // Xs: transpose + invn scale + XOR swizzle
        float4 iv4 = *(const float4*)&ivb[n0 + n4 * 4];
        float ivr[4] = {iv4.x, iv4.y, iv4.z, iv4.w};
#pragma unroll
        for (int i = 0; i < 8; ++i) {
            int c = cb + 16 * i;
            float4 xv = *(const float4*)&xb[(size_t)(c0 + c) * NPIX + n0 + n4 * 4];
            int col = 4 * (((c >> 2) ^ n4) & 31) + (c & 3);
            Xs[(n4 * 4 + 0) * 128 + col] = xv.x * ivr[0];
            Xs[(n4 * 4 + 1) * 128 + col] = xv.y * ivr[1];
            Xs[(n4 * 4 + 2) * 128 + col] = xv.z * ivr[2];
            Xs[(n4 * 4 + 3) * 128 + col] = xv.w * ivr[3];
        }
        __syncthreads();
#pragma unroll
        for (int nn = 0; nn < 32; ++nn) {
            int sx = nn >> 2;
            float4 a0 = *(const float4*)&As[nn * 64 + kg * 8];
            float4 a1 = *(const float4*)&As[nn * 64 + kg * 8 + 4];
            float4 x0 = *(const float4*)&Xs[nn * 128 + 4 * ((cg * 2) ^ sx)];
            float4 x1 = *(const float4*)&Xs[nn * 128 + 4 * ((cg * 2 + 1) ^ sx)];
            float aa[8] = {a0.x, a0.y, a0.z, a0.w, a1.x, a1.y, a1.z, a1.w};
            float xa[8] = {x0.x, x0.y, x0.z, x0.w, x1.x, x1.y, x1.z, x1.w};
#pragma unroll
            for (int i = 0; i < 8; ++i)
#pragma unroll
                for (int j = 0; j < 8; ++j)
                    acc[i][j] = fmaf(aa[i], xa[j], acc[i][j]);
        }
        __syncthreads();
    }
#pragma unroll
    for (int i = 0; i < 8; ++i) {
        int k = kg * 8 + i;
        float* pp = &part[(((size_t)s * BB + b) * KK + k) * CC + c0 + cg * 8];
        *(float4*)&pp[0] = make_float4(acc[i][0], acc[i][1], acc[i][2], acc[i][3]);
        *(float4*)&pp[4] = make_float4(acc[i][4], acc[i][5], acc[i][6], acc[i][7]);
    }
}

// ---------------------------------------------------------------------------
// k_intra: sum ns partials, asum from tile-partials, subtract asum*cent,
// intra-normalize per (b,k), accumulate per-b sum of squares.
// ---------------------------------------------------------------------------
__global__ __launch_bounds__(256) void k_intra(const float* __restrict__ part, int ns,
                                               const float* __restrict__ asum_p,
                                               const float* __restrict__ cent,
                                               float* __restrict__ out,
                                               float* __restrict__ bsum) {
    int row = blockIdx.x;                          // b*KK + k
    int b = row >> 6, k = row & 63;
    int t = threadIdx.x;
    float v0 = 0.f, v1 = 0.f;
    for (int s2 = 0; s2 < ns; ++s2) {
        const float* p = part + (((size_t)s2 * BB + b) * KK + k) * CC;
        v0 += p[t];
        v1 += p[t + 256];
    }
    float as = 0.f;
#pragma unroll
    for (int i = 0; i < NT; ++i) as += asum_p[(size_t)row * NT + i];
    v0 -= as * cent[k * CC + t];
    v1 -= as * cent[k * CC + t + 256];
    float ssq = v0 * v0 + v1 * v1;
#pragma unroll
    for (int off = 32; off; off >>= 1) ssq += __shfl_down(ssq, off, 64);
    __shared__ float red[4];
    __shared__ float s_inv;
    if ((t & 63) == 0) red[t >> 6] = ssq;
    __syncthreads();
    if (t == 0) {
        float sm = red[0] + red[1] + red[2] + red[3];
        float inv = 1.f / fmaxf(sqrtf(sm), EPSF);
        s_inv = inv;
        atomicAdd(&bsum[b], sm * inv * inv);
    }
    __syncthreads();
    float inv = s_inv;
    out[(size_t)row * CC + t]       = v0 * inv;
    out[(size_t)row * CC + t + 256] = v1 * inv;
}

// ---------------------------------------------------------------------------
__global__ __launch_bounds__(256) void k_scale(float* __restrict__ out,
                                               const float* __restrict__ bsum) {
    int idx = blockIdx.x * 256 + threadIdx.x;      // B*K*C exact
    int b = idx >> 15;                             // K*C = 32768
    out[idx] *= 1.f / fmaxf(sqrtf(bsum[b]), EPSF);
}

// ---------------------------------------------------------------------------
extern "C" void kernel_launch(void* const* d_in, const int* in_sizes, int n_in,
                              void* d_out, int out_size, void* d_ws, size_t ws_size,
                              hipStream_t stream) {
    const float* x    = (const float*)d_in[0];   // [B,C,H,W]
    const float* cent = (const float*)d_in[1];   // [K,C]
    const float* w    = (const float*)d_in[2];   // [K,C]
    float* out = (float*)d_out;

    float* ws = (float*)d_ws;
    const size_t o_at   = 0;                      // B*N*K   = 3,276,800
    const size_t o_invn = 3276800;                // B*N     =    51,200
    const size_t o_asum = o_invn + 51200;         // B*K*NT  =    51,200
    const size_t o_bsum = o_asum + 51200;         // 64
    const size_t o_wt   = o_bsum + 64;            // C*K     =    32,768
    const size_t o_part = o_wt + 32768;           // ns * B*K*C

    const size_t pelems = (size_t)BB * KK * CC;   // 1,048,576 per partial
    int ns = 0;
    const int cand[4] = {10, 5, 2, 1};
    for (int i = 0; i < 4; ++i) {
        if ((o_part + (size_t)cand[i] * pelems) * 4 <= ws_size) { ns = cand[i]; break; }
    }
    float* part = (ns > 0) ? (ws + o_part) : out;
    if (ns == 0) ns = 1;
    int nchunk = NPIX / ns;

    hipMemsetAsync(ws + o_bsum, 0, BB * sizeof(float), stream);

    k_wt    <<<dim3(8), 256, 0, stream>>>(w, ws + o_wt);
    k_fused3<<<dim3(NT, BB), 256, 0, stream>>>(x, ws + o_wt, ws + o_at,
                                               ws + o_invn, ws + o_asum);
    k_vlad3 <<<dim3(4, ns, BB), 128, 0, stream>>>(ws + o_at, x, ws + o_invn, part, nchunk);
    k_intra <<<dim3(BB * KK), 256, 0, stream>>>(part, ns, ws + o_asum, cent, out, ws + o_bsum);
    k_scale <<<dim3((BB * KK * CC) / 256), 256, 0, stream>>>(out, ws + o_bsum);
}

// Round 7
// 88.595 us; speedup vs baseline: 11.7195x; 1.8000x over previous
//
#include <hip/hip_runtime.h>
#include <math.h>

#define BB   32
#define CC   512
#define NPIX 1600
#define KK   64
#define NT   25        // 64-wide n-tiles in pass A
#define EPSF 1e-12f

typedef __attribute__((ext_vector_type(8))) short bf16x8;
typedef __attribute__((ext_vector_type(4))) float f32x4;
#define MFMA16 __builtin_amdgcn_mfma_f32_16x16x32_bf16

__device__ __forceinline__ ushort f2bf(float f) {
    union { float f; uint u; } v; v.f = f;
    uint r = v.u + 0x7FFFu + ((v.u >> 16) & 1u);   // round-to-nearest-even
    return (ushort)(r >> 16);
}

// ---------------------------------------------------------------------------
// k_gemm1m: per (64n tile, b) with MFMA 16x16x32 bf16:
//   logits[k][n] = sum_c w[k,c] * x[b,c,n]        (bf16 inputs, fp32 acc)
//   ssq[n] from fp32 staging regs -> invn
//   softmax over k (scaled by invn), a' = a*invn -> a_t[b][k][n] bf16
//   asum_p[b][k][tile] (unscaled a sums)
// D[k-rows][n-cols]: A-frag = w tile [64k][32c] bf16 LDS (c-contig),
// B-frag = x tile [64n][32c] bf16 LDS (transposed at staging, 2x2-pack).
// 16B-granule XOR swizzle (g' = g ^ ((row>>1)&3)) -> 2-way reads (free).
// ---------------------------------------------------------------------------
__global__ __launch_bounds__(256) void k_gemm1m(const float* __restrict__ x,
                                                const float* __restrict__ w,
                                                ushort* __restrict__ a_t,
                                                float* __restrict__ asum_p) {
    int tile = blockIdx.x, b = blockIdx.y;
    int n0 = tile * 64;
    __shared__ __align__(16) ushort Xs[2][64 * 32];   // [n][swz c] bf16
    __shared__ __align__(16) ushort Wsh[2][64 * 32];  // [k][swz c] bf16
    __shared__ __align__(16) float red[16 * 64];
    __shared__ __align__(16) float asw[4 * 64];
    __shared__ __align__(16) float ivs[64];
    int t = threadIdx.x;
    int lane = t & 63, wv = t >> 6;
    int sc2 = (t & 15) * 2;        // X staging: c pair base (0..30)
    int sn4 = (t >> 4) * 4;        // X staging: 4 n rows
    int wk  = t >> 2;              // W staging: k row (0..63)
    int wc8 = (t & 3) * 8;         // W staging: c chunk
    const float* xb = x + (size_t)b * CC * NPIX + n0;
    f32x4 acc[4] = {};
    float ss[4] = {0.f, 0.f, 0.f, 0.f};

    float4 xa, xc, wa, wc2;
    // ---- prologue: load + stage c-block 0 into buf 0
    xa  = *(const float4*)&xb[(size_t)sc2 * NPIX + sn4];
    xc  = *(const float4*)&xb[(size_t)(sc2 + 1) * NPIX + sn4];
    wa  = *(const float4*)&w[(size_t)wk * CC + wc8];
    wc2 = *(const float4*)&w[(size_t)wk * CC + wc8 + 4];
    {
        uint* XU = (uint*)Xs[0]; uint* WU = (uint*)Wsh[0];
        float va[4] = {xa.x, xa.y, xa.z, xa.w};
        float vc[4] = {xc.x, xc.y, xc.z, xc.w};
#pragma unroll
        for (int j = 0; j < 4; ++j) {
            ss[j] += va[j] * va[j] + vc[j] * vc[j];
            int row = sn4 + j;
            int gp = ((t & 15) >> 2) ^ ((row >> 1) & 3);
            XU[row * 16 + gp * 4 + (t & 3)] =
                (uint)f2bf(va[j]) | ((uint)f2bf(vc[j]) << 16);
        }
        uint4 wp;
        wp.x = (uint)f2bf(wa.x)  | ((uint)f2bf(wa.y)  << 16);
        wp.y = (uint)f2bf(wa.z)  | ((uint)f2bf(wa.w)  << 16);
        wp.z = (uint)f2bf(wc2.x) | ((uint)f2bf(wc2.y) << 16);
        wp.w = (uint)f2bf(wc2.z) | ((uint)f2bf(wc2.w) << 16);
        int gp = (t & 3) ^ ((wk >> 1) & 3);
        *(uint4*)&WU[wk * 16 + gp * 4] = wp;
    }
    __syncthreads();

    int cur = 0;
    for (int it = 0; it < 16; ++it) {
        bool pre = (it < 15);
        if (pre) {
            int c0 = (it + 1) * 32;
            xa  = *(const float4*)&xb[(size_t)(c0 + sc2) * NPIX + sn4];
            xc  = *(const float4*)&xb[(size_t)(c0 + sc2 + 1) * NPIX + sn4];
            wa  = *(const float4*)&w[(size_t)wk * CC + c0 + wc8];
            wc2 = *(const float4*)&w[(size_t)wk * CC + c0 + wc8 + 4];
        }
        // ---- MFMA on current buffer
        {
            const ushort* Xc = Xs[cur];
            const ushort* Wc = Wsh[cur];
            int rn = wv * 16 + (lane & 15);
            int gB = (lane >> 4) ^ ((rn >> 1) & 3);
            bf16x8 bfr = *(const bf16x8*)&Xc[rn * 32 + gB * 8];
#pragma unroll
            for (int kf = 0; kf < 4; ++kf) {
                int rk = kf * 16 + (lane & 15);
                int gA = (lane >> 4) ^ ((rk >> 1) & 3);
                bf16x8 afr = *(const bf16x8*)&Wc[rk * 32 + gA * 8];
                acc[kf] = MFMA16(afr, bfr, acc[kf], 0, 0, 0);
            }
        }
        if (pre) {
            uint* XU = (uint*)Xs[cur ^ 1]; uint* WU = (uint*)Wsh[cur ^ 1];
            float va[4] = {xa.x, xa.y, xa.z, xa.w};
            float vc[4] = {xc.x, xc.y, xc.z, xc.w};
#pragma unroll
            for (int j = 0; j < 4; ++j) {
                ss[j] += va[j] * va[j] + vc[j] * vc[j];
                int row = sn4 + j;
                int gp = ((t & 15) >> 2) ^ ((row >> 1) & 3);
                XU[row * 16 + gp * 4 + (t & 3)] =
                    (uint)f2bf(va[j]) | ((uint)f2bf(vc[j]) << 16);
            }
            uint4 wp;
            wp.x = (uint)f2bf(wa.x)  | ((uint)f2bf(wa.y)  << 16);
            wp.y = (uint)f2bf(wa.z)  | ((uint)f2bf(wa.w)  << 16);
            wp.z = (uint)f2bf(wc2.x) | ((uint)f2bf(wc2.y) << 16);
            wp.w = (uint)f2bf(wc2.z) | ((uint)f2bf(wc2.w) << 16);
            int gp = (t & 3) ^ ((wk >> 1) & 3);
            *(uint4*)&WU[wk * 16 + gp * 4] = wp;
        }
        __syncthreads();
        cur ^= 1;
    }

    // ---- ssq reduce -> invn (LDS only, no global invn needed)
#pragma unroll
    for (int j = 0; j < 4; ++j) red[(t & 15) * 64 + sn4 + j] = ss[j];
    __syncthreads();
    if (t < 64) {
        float s = 0.f;
#pragma unroll
        for (int i = 0; i < 16; ++i) s += red[i * 64 + t];
        ivs[t] = 1.f / fmaxf(sqrtf(s), EPSF);
    }
    __syncthreads();

    int nloc = wv * 16 + (lane & 15);
    float invl = ivs[nloc];

    // ---- softmax over k (rows).  Lane holds 16 k's for ONE n-col.
    float lv[4][4];
    float mm = -1e30f;
#pragma unroll
    for (int kf = 0; kf < 4; ++kf)
#pragma unroll
        for (int r = 0; r < 4; ++r) {
            lv[kf][r] = acc[kf][r] * invl;
            mm = fmaxf(mm, lv[kf][r]);
        }
    mm = fmaxf(mm, __shfl_xor(mm, 16));
    mm = fmaxf(mm, __shfl_xor(mm, 32));
    float ev[4][4], s = 0.f;
#pragma unroll
    for (int kf = 0; kf < 4; ++kf)
#pragma unroll
        for (int r = 0; r < 4; ++r) {
            ev[kf][r] = expf(lv[kf][r] - mm);
            s += ev[kf][r];
        }
    s += __shfl_xor(s, 16);
    s += __shfl_xor(s, 32);
    float sd = 1.f / s;

    // ---- asum partials (unscaled a), reduce over the wave's 16 n
    float av[4][4];
#pragma unroll
    for (int kf = 0; kf < 4; ++kf)
#pragma unroll
        for (int r = 0; r < 4; ++r) av[kf][r] = ev[kf][r] * sd;
#pragma unroll
    for (int off = 1; off < 16; off <<= 1)
#pragma unroll
        for (int kf = 0; kf < 4; ++kf)
#pragma unroll
            for (int r = 0; r < 4; ++r) av[kf][r] += __shfl_xor(av[kf][r], off);
    if ((lane & 15) == 0) {
#pragma unroll
        for (int kf = 0; kf < 4; ++kf)
#pragma unroll
            for (int r = 0; r < 4; ++r)
                asw[wv * 64 + kf * 16 + (lane >> 4) * 4 + r] = av[kf][r];
    }

    // ---- a' = a * invn -> a_t[b][k][n] bf16 (16-lane contiguous n writes)
    ushort* ab = a_t + (size_t)b * KK * NPIX;
#pragma unroll
    for (int kf = 0; kf < 4; ++kf)
#pragma unroll
        for (int r = 0; r < 4; ++r) {
            int k = kf * 16 + (lane >> 4) * 4 + r;
            ab[(size_t)k * NPIX + n0 + nloc] = f2bf(ev[kf][r] * sd * invl);
        }
    __syncthreads();
    if (t < 64) {
        float a4 = asw[t] + asw[64 + t] + asw[128 + t] + asw[192 + t];
        asum_p[((size_t)b * KK + t) * NT + tile] = a4;
    }
}

// ---------------------------------------------------------------------------
// k_vladm: part[s][b][k][c] = sum_{n in chunk} a'[k,n] * x[c,n]  (MFMA)
// D[k-rows][c-cols] per (64c tile, chunk s, b).
// A-frag = a_t tile [64k][32n] bf16 (linear b128 staging from a_t[b][k][n]),
// B-frag = x tile [64c][32n] bf16 (rows match global layout; cvt at staging).
// Same granule XOR swizzle; double-buffered, 1 barrier/step.
// ---------------------------------------------------------------------------
__global__ __launch_bounds__(256) void k_vladm(const ushort* __restrict__ a_t,
                                               const float* __restrict__ x,
                                               float* __restrict__ part,
                                               int nchunk) {
    int c0 = blockIdx.x * 64;
    int s  = blockIdx.y;
    int b  = blockIdx.z;
    __shared__ __align__(16) ushort Ash[2][64 * 32];  // [k][swz n]
    __shared__ __align__(16) ushort Xsh[2][64 * 32];  // [c][swz n]
    int t = threadIdx.x;
    int lane = t & 63, wv = t >> 6;
    int sk  = t >> 2;              // staging row (k for A, c for X)
    int sn8 = (t & 3) * 8;         // staging n chunk
    const ushort* ab = a_t + (size_t)b * KK * NPIX;
    const float*  xb = x + (size_t)b * CC * NPIX;
    f32x4 acc[4] = {};
    int nbase = s * nchunk;
    int niters = nchunk / 32;

    uint4 ar; float4 x0, x1;
    // ---- prologue
    ar = *(const uint4*)&ab[(size_t)sk * NPIX + nbase + sn8];
    x0 = *(const float4*)&xb[(size_t)(c0 + sk) * NPIX + nbase + sn8];
    x1 = *(const float4*)&xb[(size_t)(c0 + sk) * NPIX + nbase + sn8 + 4];
    {
        uint* AU = (uint*)Ash[0]; uint* XU = (uint*)Xsh[0];
        int gp = (t & 3) ^ ((sk >> 1) & 3);
        *(uint4*)&AU[sk * 16 + gp * 4] = ar;
        uint4 xp;
        xp.x = (uint)f2bf(x0.x) | ((uint)f2bf(x0.y) << 16);
        xp.y = (uint)f2bf(x0.z) | ((uint)f2bf(x0.w) << 16);
        xp.z = (uint)f2bf(x1.x) | ((uint)f2bf(x1.y) << 16);
        xp.w = (uint)f2bf(x1.z) | ((uint)f2bf(x1.w) << 16);
        *(uint4*)&XU[sk * 16 + gp * 4] = xp;
    }
    __syncthreads();

    int cur = 0;
    for (int it = 0; it < niters; ++it) {
        bool pre = (it + 1 < niters);
        if (pre) {
            int ng = nbase + (it + 1) * 32;
            ar = *(const uint4*)&ab[(size_t)sk * NPIX + ng + sn8];
            x0 = *(const float4*)&xb[(size_t)(c0 + sk) * NPIX + ng + sn8];
            x1 = *(const float4*)&xb[(size_t)(c0 + sk) * NPIX + ng + sn8 + 4];
        }
        {
            const ushort* Ac = Ash[cur];
            const ushort* Xc = Xsh[cur];
            int rc = wv * 16 + (lane & 15);
            int gB = (lane >> 4) ^ ((rc >> 1) & 3);
            bf16x8 bfr = *(const bf16x8*)&Xc[rc * 32 + gB * 8];
#pragma unroll
            for (int kf = 0; kf < 4; ++kf) {
                int rk = kf * 16 + (lane & 15);
                int gA = (lane >> 4) ^ ((rk >> 1) & 3);
                bf16x8 afr = *(const bf16x8*)&Ac[rk * 32 + gA * 8];
                acc[kf] = MFMA16(afr, bfr, acc[kf], 0, 0, 0);
            }
        }
        if (pre) {
            uint* AU = (uint*)Ash[cur ^ 1]; uint* XU = (uint*)Xsh[cur ^ 1];
            int gp = (t & 3) ^ ((sk >> 1) & 3);
            *(uint4*)&AU[sk * 16 + gp * 4] = ar;
            uint4 xp;
            xp.x = (uint)f2bf(x0.x) | ((uint)f2bf(x0.y) << 16);
            xp.y = (uint)f2bf(x0.z) | ((uint)f2bf(x0.w) << 16);
            xp.z = (uint)f2bf(x1.x) | ((uint)f2bf(x1.y) << 16);
            xp.w = (uint)f2bf(x1.z) | ((uint)f2bf(x1.w) << 16);
            *(uint4*)&XU[sk * 16 + gp * 4] = xp;
        }
        __syncthreads();
        cur ^= 1;
    }

    // ---- epilogue: D[k][c] -> part[s][b][k][c]
#pragma unroll
    for (int kf = 0; kf < 4; ++kf)
#pragma unroll
        for (int r = 0; r < 4; ++r) {
            int k = kf * 16 + (lane >> 4) * 4 + r;
            int c = c0 + wv * 16 + (lane & 15);
            part[(((size_t)s * BB + b) * KK + k) * CC + c] = acc[kf][r];
        }
}

// ---------------------------------------------------------------------------
// k_intra: sum ns partials, asum from tile-partials, subtract asum*cent,
// intra-normalize per (b,k), accumulate per-b sum of squares.
// ---------------------------------------------------------------------------
__global__ __launch_bounds__(256) void k_intra(const float* __restrict__ part, int ns,
                                               const float* __restrict__ asum_p,
                                               const float* __restrict__ cent,
                                               float* __restrict__ out,
                                               float* __restrict__ bsum) {
    int row = blockIdx.x;                          // b*KK + k
    int b = row >> 6, k = row & 63;
    int t = threadIdx.x;
    float v0 = 0.f, v1 = 0.f;
    for (int s2 = 0; s2 < ns; ++s2) {
        const float* p = part + (((size_t)s2 * BB + b) * KK + k) * CC;
        v0 += p[t];
        v1 += p[t + 256];
    }
    float as = 0.f;
#pragma unroll
    for (int i = 0; i < NT; ++i) as += asum_p[(size_t)row * NT + i];
    v0 -= as * cent[k * CC + t];
    v1 -= as * cent[k * CC + t + 256];
    float ssq = v0 * v0 + v1 * v1;
#pragma unroll
    for (int off = 32; off; off >>= 1) ssq += __shfl_down(ssq, off, 64);
    __shared__ float red[4];
    __shared__ float s_inv;
    if ((t & 63) == 0) red[t >> 6] = ssq;
    __syncthreads();
    if (t == 0) {
        float sm = red[0] + red[1] + red[2] + red[3];
        float inv = 1.f / fmaxf(sqrtf(sm), EPSF);
        s_inv = inv;
        atomicAdd(&bsum[b], sm * inv * inv);
    }
    __syncthreads();
    float inv = s_inv;
    out[(size_t)row * CC + t]       = v0 * inv;
    out[(size_t)row * CC + t + 256] = v1 * inv;
}

// ---------------------------------------------------------------------------
__global__ __launch_bounds__(256) void k_scale(float* __restrict__ out,
                                               const float* __restrict__ bsum) {
    int idx = blockIdx.x * 256 + threadIdx.x;      // B*K*C exact
    int b = idx >> 15;                             // K*C = 32768
    out[idx] *= 1.f / fmaxf(sqrtf(bsum[b]), EPSF);
}

// ---------------------------------------------------------------------------
extern "C" void kernel_launch(void* const* d_in, const int* in_sizes, int n_in,
                              void* d_out, int out_size, void* d_ws, size_t ws_size,
                              hipStream_t stream) {
    const float* x    = (const float*)d_in[0];   // [B,C,H,W]
    const float* cent = (const float*)d_in[1];   // [K,C]
    const float* w    = (const float*)d_in[2];   // [K,C]
    float* out = (float*)d_out;

    char* wsb = (char*)d_ws;
    const size_t oa_at   = 0;                                  // bf16 B*K*N = 6,553,600 B
    const size_t oa_asum = oa_at + (size_t)BB * KK * NPIX * 2; // f32 B*K*NT =   204,800 B
    const size_t oa_bsum = oa_asum + (size_t)BB * KK * NT * 4; //               128 B
    const size_t oa_part = oa_bsum + 128;
    ushort* a_t   = (ushort*)(wsb + oa_at);
    float* asum_p = (float*)(wsb + oa_asum);
    float* bsum   = (float*)(wsb + oa_bsum);

    // pick ns with nchunk = 1600/ns a multiple of 32: {5, 2, 1}
    const size_t pbytes = (size_t)BB * KK * CC * 4;            // 4 MB per partial
    int ns = 0;
    const int cand[3] = {5, 2, 1};
    for (int i = 0; i < 3; ++i) {
        if (oa_part + (size_t)cand[i] * pbytes <= ws_size) { ns = cand[i]; break; }
    }
    float* part = (ns > 0) ? (float*)(wsb + oa_part) : out;    // ns=1 fallback -> d_out
    if (ns == 0) ns = 1;
    int nchunk = NPIX / ns;

    hipMemsetAsync(bsum, 0, BB * sizeof(float), stream);

    k_gemm1m<<<dim3(NT, BB), 256, 0, stream>>>(x, w, a_t, asum_p);
    k_vladm <<<dim3(CC / 64, ns, BB), 256, 0, stream>>>(a_t, x, part, nchunk);
    k_intra <<<dim3(BB * KK), 256, 0, stream>>>(part, ns, asum_p, cent, out, bsum);
    k_scale <<<dim3((BB * KK * CC) / 256), 256, 0, stream>>>(out, bsum);
}